// Round 1
// baseline (252.571 us; speedup 1.0000x reference)
//
#include <hip/hip_runtime.h>
#include <stdint.h>

// Problem geometry (fixed by reference):
//   logits [8,4096,1024] f32, primitives [1024,1024] f32
//   outputs: embeddings [8,4096,1024] f32 | indices [8,4096] (as f32) | counts [1024] (as f32)
#define NROWS   32768        // 8*4096
#define KDIM    1024
#define EMB_OFF 33554432     // 8*4096*1024
#define IDX_OFF 33554432
#define CNT_OFF 33587200     // EMB + 32768

__device__ __forceinline__ uint32_t rotl32(uint32_t x, int r) {
    return (x << r) | (x >> (32 - r));
}

// threefry2x32-20 with key (k0=0, k1=42), input words (x0=0, x1=ctr).
// Returns o0 ^ o1 — JAX partitionable 32-bit random_bits.
__device__ __forceinline__ uint32_t threefry_bits(uint32_t ctr) {
    const uint32_t ks0 = 0u;
    const uint32_t ks1 = 42u;
    const uint32_t ks2 = 0x1BD11BDAu ^ 0u ^ 42u;   // 0x1BD11BF0

    uint32_t x0 = 0u + ks0;
    uint32_t x1 = ctr + ks1;

    // group 0: rotations 13,15,26,6
    x0 += x1; x1 = rotl32(x1, 13); x1 ^= x0;
    x0 += x1; x1 = rotl32(x1, 15); x1 ^= x0;
    x0 += x1; x1 = rotl32(x1, 26); x1 ^= x0;
    x0 += x1; x1 = rotl32(x1,  6); x1 ^= x0;
    x0 += ks1; x1 += ks2 + 1u;
    // group 1: rotations 17,29,16,24
    x0 += x1; x1 = rotl32(x1, 17); x1 ^= x0;
    x0 += x1; x1 = rotl32(x1, 29); x1 ^= x0;
    x0 += x1; x1 = rotl32(x1, 16); x1 ^= x0;
    x0 += x1; x1 = rotl32(x1, 24); x1 ^= x0;
    x0 += ks2; x1 += ks0 + 2u;
    // group 2: rotations 13,15,26,6
    x0 += x1; x1 = rotl32(x1, 13); x1 ^= x0;
    x0 += x1; x1 = rotl32(x1, 15); x1 ^= x0;
    x0 += x1; x1 = rotl32(x1, 26); x1 ^= x0;
    x0 += x1; x1 = rotl32(x1,  6); x1 ^= x0;
    x0 += ks0; x1 += ks1 + 3u;
    // group 3: rotations 17,29,16,24
    x0 += x1; x1 = rotl32(x1, 17); x1 ^= x0;
    x0 += x1; x1 = rotl32(x1, 29); x1 ^= x0;
    x0 += x1; x1 = rotl32(x1, 16); x1 ^= x0;
    x0 += x1; x1 = rotl32(x1, 24); x1 ^= x0;
    x0 += ks1; x1 += ks2 + 4u;
    // group 4: rotations 13,15,26,6
    x0 += x1; x1 = rotl32(x1, 13); x1 ^= x0;
    x0 += x1; x1 = rotl32(x1, 15); x1 ^= x0;
    x0 += x1; x1 = rotl32(x1, 26); x1 ^= x0;
    x0 += x1; x1 = rotl32(x1,  6); x1 ^= x0;
    x0 += ks2; x1 += ks0 + 5u;

    return x0 ^ x1;
}

// JAX: uniform(key, shape, f32, minval=tiny, maxval=1) then -log(-log(u)).
// In f32, floats*(1-tiny)+tiny; max(tiny, .) reduces exactly to fmaxf(f, tiny).
__device__ __forceinline__ float gumbel_from_bits(uint32_t bits) {
    float f = __uint_as_float((bits >> 9) | 0x3f800000u) - 1.0f;  // [0,1)
    float u = fmaxf(f, 1.17549435e-38f);
    return -logf(-logf(u));   // precise logf: ulp fidelity protects argmax near-ties
}

__global__ __launch_bounds__(256) void gumbel_argmax_gather(
    const float* __restrict__ logits,
    const float* __restrict__ prim,
    float* __restrict__ out,
    int* __restrict__ counts)
{
    const int row = blockIdx.x;          // 0..32767 = b*4096+s, row-major flat
    const int tid = threadIdx.x;         // 0..255
    const uint32_t base = (uint32_t)row * (uint32_t)KDIM;

    // --- per-thread argmax over 4 strided columns (ascending k: first-index ties kept)
    float bv = -INFINITY;
    int   bk = 0;
    #pragma unroll
    for (int m = 0; m < 4; ++m) {
        const int k = tid + m * 256;
        const uint32_t ctr = base + (uint32_t)k;     // flat element index < 2^32
        const float g = gumbel_from_bits(threefry_bits(ctr));
        const float z = logits[base + (uint32_t)k] + g;  // argmax(z) == argmax(softmax(z/tau))
        if (z > bv) { bv = z; bk = k; }
    }

    // --- wave (64-lane) reduction, first-index tie-break
    #pragma unroll
    for (int off = 32; off > 0; off >>= 1) {
        const float ov = __shfl_down(bv, off);
        const int   ok = __shfl_down(bk, off);
        if (ov > bv || (ov == bv && ok < bk)) { bv = ov; bk = ok; }
    }

    __shared__ float s_v[4];
    __shared__ int   s_k[4];
    __shared__ int   s_idx;
    const int wave = tid >> 6;
    if ((tid & 63) == 0) { s_v[wave] = bv; s_k[wave] = bk; }
    __syncthreads();

    if (tid == 0) {
        float v = s_v[0]; int kk = s_k[0];
        #pragma unroll
        for (int w = 1; w < 4; ++w) {
            if (s_v[w] > v || (s_v[w] == v && s_k[w] < kk)) { v = s_v[w]; kk = s_k[w]; }
        }
        s_idx = kk;
        out[IDX_OFF + row] = (float)kk;          // indices stored as f32 values
        atomicAdd(&counts[kk], 1);               // device-scope histogram in d_ws
    }
    __syncthreads();

    // --- gather primitives[idx] row -> embeddings row (float4, fully coalesced)
    const int idx = s_idx;
    const float4* __restrict__ src = (const float4*)(prim + (size_t)idx * KDIM);
    float4* __restrict__ dst = (float4*)(out + (size_t)row * KDIM);
    dst[tid] = src[tid];
}

__global__ void counts_to_float(const int* __restrict__ counts, float* __restrict__ out) {
    const int t = blockIdx.x * blockDim.x + threadIdx.x;
    if (t < KDIM) out[t] = (float)counts[t];
}

extern "C" void kernel_launch(void* const* d_in, const int* in_sizes, int n_in,
                              void* d_out, int out_size, void* d_ws, size_t ws_size,
                              hipStream_t stream) {
    const float* logits = (const float*)d_in[0];   // [8,4096,1024] f32
    const float* prim   = (const float*)d_in[1];   // [1024,1024]   f32
    float* out = (float*)d_out;
    int*   cnt = (int*)d_ws;                       // 1024 ints of scratch

    // d_ws is poisoned 0xAA before every launch — zero the histogram (graph-safe memset).
    hipMemsetAsync(d_ws, 0, KDIM * sizeof(int), stream);

    gumbel_argmax_gather<<<NROWS, 256, 0, stream>>>(logits, prim, out, cnt);
    counts_to_float<<<4, 256, 0, stream>>>(cnt, out + CNT_OFF);
}